// Round 14
// baseline (572.809 us; speedup 1.0000x reference)
//
#include <hip/hip_runtime.h>

#define B_   128
#define L_   400
#define V_   50000
#define E_   512
#define H2_  1024
#define M_   1024
#define OOV_ 50
#define VE_  50050   // V + OOV
#define BL_  51200   // B*L

typedef __attribute__((ext_vector_type(8))) short short8;
typedef __attribute__((ext_vector_type(4))) float f32x4;

__device__ __forceinline__ unsigned short f2bf(float f){
  unsigned int u = __builtin_bit_cast(unsigned int, f);
  u = (u + 0x7FFFu + ((u >> 16) & 1u)) >> 16;
  return (unsigned short)u;
}
__device__ __forceinline__ float bf2f(unsigned short s){
  unsigned int u = ((unsigned int)s) << 16;
  return __builtin_bit_cast(float, u);
}
// truncating fp32->bf16 (1 VALU op)
__device__ __forceinline__ short f2bf_t(float f){
  return (short)(__builtin_bit_cast(unsigned int, f) >> 16);
}

__device__ __forceinline__ void gl_lds16(const void* g, void* l){
  __builtin_amdgcn_global_load_lds(
      (const __attribute__((address_space(1))) unsigned int*)g,
      (__attribute__((address_space(3))) unsigned int*)l, 16, 0, 0);
}

__device__ __forceinline__ float wredsum(float v){
  #pragma unroll
  for (int o = 32; o > 0; o >>= 1) v += __shfl_xor(v, o);
  return v;
}
__device__ __forceinline__ float wredmax(float v){
  #pragma unroll
  for (int o = 32; o > 0; o >>= 1) v = fmaxf(v, __shfl_xor(v, o));
  return v;
}

// ---- mb fp32 [51200][1024] -> tiled+swizzled bf16; one 16B-unit per thread ----
__device__ __forceinline__ void mb_convert_unit(const float* __restrict__ mb,
                                                unsigned char* __restrict__ mbT, int u){
  int gr  = u >> 7;
  int m16 = u & 127;
  const float* src = mb + (size_t)gr * 1024 + m16 * 8;
  float4 f0 = *(const float4*)src;
  float4 f1 = *(const float4*)(src + 4);
  uint4 w;
  w.x = (unsigned)f2bf(f0.x) | ((unsigned)f2bf(f0.y) << 16);
  w.y = (unsigned)f2bf(f0.z) | ((unsigned)f2bf(f0.w) << 16);
  w.z = (unsigned)f2bf(f1.x) | ((unsigned)f2bf(f1.y) << 16);
  w.w = (unsigned)f2bf(f1.z) | ((unsigned)f2bf(f1.w) << 16);
  int panel = gr >> 7, r = gr & 127;
  int ks = m16 >> 3, c16 = m16 & 7;
  size_t dst = (size_t)panel * 262144 + (size_t)ks * 16384
             + (size_t)((r * 128 + c16 * 16) ^ ((r & 7) << 4));
  *(uint4*)(mbT + dst) = w;
}

// ---------------- pre: cvt share | W_mem transpose | embed gather | zeroing ----------------
__global__ void pre_kernel(const float* __restrict__ mb, unsigned char* __restrict__ mbT,
                           const float* __restrict__ Wm, unsigned char* __restrict__ WTt,
                           const int* __restrict__ y, const float* __restrict__ emb,
                           float* __restrict__ yemb, float* __restrict__ zeroA,
                           float* __restrict__ ctx)
{
  __shared__ float tile[32][33];
  int bid = blockIdx.x, t = threadIdx.x;
  if (bid < 6400){                          // convert share [0, 6400)
    mb_convert_unit(mb, mbT, bid * 256 + t);
  } else if (bid < 7424){                   // W_mem [k][n] -> WTt (cols as rows)
    int b2 = bid - 6400;
    int n0 = (b2 & 31) * 32, k0 = (b2 >> 5) * 32;
    int tx = t & 31, ty = t >> 5;
    #pragma unroll
    for (int i = 0; i < 32; i += 8) tile[ty + i][tx] = Wm[(size_t)(k0 + ty + i) * H2_ + n0 + tx];
    __syncthreads();
    if (t < 128){
      int nn = t & 31, k16 = t >> 5;
      int col = n0 + nn, kb = k0 + k16 * 8;
      uint4 w;
      w.x = (unsigned)f2bf(tile[k16*8+0][nn]) | ((unsigned)f2bf(tile[k16*8+1][nn]) << 16);
      w.y = (unsigned)f2bf(tile[k16*8+2][nn]) | ((unsigned)f2bf(tile[k16*8+3][nn]) << 16);
      w.z = (unsigned)f2bf(tile[k16*8+4][nn]) | ((unsigned)f2bf(tile[k16*8+5][nn]) << 16);
      w.w = (unsigned)f2bf(tile[k16*8+6][nn]) | ((unsigned)f2bf(tile[k16*8+7][nn]) << 16);
      int cpn = col >> 7, r = col & 127;
      int ks = kb >> 6, c16 = (kb & 63) >> 3;
      size_t dst = (size_t)cpn * 262144 + (size_t)ks * 16384
                 + (size_t)((r * 128 + c16 * 16) ^ ((r & 7) << 4));
      *(uint4*)(WTt + dst) = w;
    }
  } else if (bid < 7488){                   // embed gather
    int idx = (bid - 7424) * 256 + t;
    int b  = idx >> 7;
    int c4 = (idx & 127) << 2;
    float4 v = *(const float4*)(emb + (size_t)y[b] * E_ + c4);
    *(float4*)(yemb + (size_t)b * E_ + c4) = v;
  } else if (bid < 8384){                   // zero gi|gh|dec (917,504 floats = 896 blocks)
    int u = (bid - 7488) * 256 + t;
    float4 z = {0.f, 0.f, 0.f, 0.f};
    *(float4*)(zeroA + (size_t)u * 4) = z;
  } else {                                  // zero ctx (131,072 floats = 128 blocks)
    int u = (bid - 8384) * 256 + t;
    float4 z = {0.f, 0.f, 0.f, 0.f};
    *(float4*)(ctx + (size_t)u * 4) = z;
  }
}

// ---------------- generic C[128,N] += A[128,K] @ W[K,N] (+bias), fp32 A, atomicAdd ----------------
__device__ __forceinline__ void gemm128_body(int bx, int by,
                               const float* __restrict__ A, int lda,
                               const float* __restrict__ W, int ldw,
                               const float* __restrict__ bias,
                               float* __restrict__ C, int ldc,
                               int N, int kChunk, int addBias)
{
  int tid = threadIdx.x;
  int wv = tid >> 6, lane = tid & 63, lr = lane & 15, lhi = lane >> 4;
  int colBase = bx * 128 + wv * 32;
  int colL[2];
  colL[0] = min(colBase + lr, N - 1);
  colL[1] = min(colBase + 16 + lr, N - 1);
  int k0 = by * kChunk;

  f32x4 zero = {0.f, 0.f, 0.f, 0.f};
  f32x4 acc[8][2];
  #pragma unroll
  for (int r = 0; r < 8; r++){ acc[r][0] = zero; acc[r][1] = zero; }

  int nks = kChunk >> 5;
  for (int ks = 0; ks < nks; ++ks){
    int k = k0 + ks * 32 + lhi * 8;
    short8 bf[2];
    #pragma unroll
    for (int cf = 0; cf < 2; cf++){
      #pragma unroll
      for (int j = 0; j < 8; j++)
        bf[cf][j] = (short)f2bf(W[(size_t)(k + j) * ldw + colL[cf]]);
    }
    #pragma unroll
    for (int rf = 0; rf < 8; rf++){
      const float* ap = A + (size_t)(rf * 16 + lr) * lda + k;
      float4 a0 = *(const float4*)ap;
      float4 a1 = *(const float4*)(ap + 4);
      short8 af;
      af[0]=(short)f2bf(a0.x); af[1]=(short)f2bf(a0.y); af[2]=(short)f2bf(a0.z); af[3]=(short)f2bf(a0.w);
      af[4]=(short)f2bf(a1.x); af[5]=(short)f2bf(a1.y); af[6]=(short)f2bf(a1.z); af[7]=(short)f2bf(a1.w);
      acc[rf][0] = __builtin_amdgcn_mfma_f32_16x16x32_bf16(af, bf[0], acc[rf][0], 0, 0, 0);
      acc[rf][1] = __builtin_amdgcn_mfma_f32_16x16x32_bf16(af, bf[1], acc[rf][1], 0, 0, 0);
    }
  }

  bool addB = addBias && (by == 0);
  #pragma unroll
  for (int cf = 0; cf < 2; cf++){
    int col = colBase + cf * 16 + lr;
    bool ok = col < N;
    float bv = addB ? bias[colL[cf]] : 0.f;
    #pragma unroll
    for (int rf = 0; rf < 8; rf++)
      #pragma unroll
      for (int i = 0; i < 4; i++){
        int row = rf * 16 + lhi * 4 + i;
        if (ok) atomicAdd(&C[(size_t)row * ldc + col], acc[rf][cf][i] + bv);
      }
  }
}

// gi (48 blocks) + gh (96 blocks) + convert share [6400, 12800)
__launch_bounds__(256)
__global__ void gigh_kernel(const float* __restrict__ yemb, const float* __restrict__ hin,
                            const float* __restrict__ W_ih, const float* __restrict__ W_hh,
                            float* __restrict__ gi, float* __restrict__ gh,
                            const float* __restrict__ mb, unsigned char* __restrict__ mbT){
  int bid = blockIdx.x;
  if (bid < 48)
    gemm128_body(bid % 24, bid / 24, yemb, E_,  W_ih, 3 * H2_, nullptr, gi, 3 * H2_, 3 * H2_, 256, 0);
  else if (bid < 144){
    int b2 = bid - 48;
    gemm128_body(b2 % 24, b2 / 24, hin, H2_, W_hh, 3 * H2_, nullptr, gh, 3 * H2_, 3 * H2_, 256, 0);
  } else {
    mb_convert_unit(mb, mbT, (6400 + bid - 144) * 256 + threadIdx.x);
  }
}

// ---------------- GRU gates (512 blocks) + convert share [12800, 19200) ----------------
__global__ void gru_gates_kernel(const float* __restrict__ gi, const float* __restrict__ gh,
                                 const float* __restrict__ bih, const float* __restrict__ bhh,
                                 const float* __restrict__ h0, float* __restrict__ hn,
                                 const float* __restrict__ mb, unsigned char* __restrict__ mbT){
  int bid = blockIdx.x;
  if (bid >= 512){
    mb_convert_unit(mb, mbT, (12800 + bid - 512) * 256 + threadIdx.x);
    return;
  }
  int idx = bid * 256 + threadIdx.x;
  int b = idx >> 10, j = idx & 1023;
  const float* gib = gi + (size_t)b * 3072;
  const float* ghb = gh + (size_t)b * 3072;
  float ir = gib[j]        + bih[j],        hr = ghb[j]        + bhh[j];
  float iz = gib[j + 1024] + bih[j + 1024], hz = ghb[j + 1024] + bhh[j + 1024];
  float in_= gib[j + 2048] + bih[j + 2048], hnv= ghb[j + 2048] + bhh[j + 2048];
  float r = 1.f / (1.f + __expf(-(ir + hr)));
  float z = 1.f / (1.f + __expf(-(iz + hz)));
  float n = tanhf(in_ + r * hnv);
  hn[idx] = (1.f - z) * n + z * h0[idx];
}

// dec GEMM (32 blocks) + convert share [19200, 25600)
__launch_bounds__(256)
__global__ void dec_kernel(const float* __restrict__ hnext, const float* __restrict__ W_dec,
                           const float* __restrict__ b_dec, float* __restrict__ dec,
                           const float* __restrict__ mb, unsigned char* __restrict__ mbT){
  int bid = blockIdx.x;
  if (bid < 32)
    gemm128_body(bid & 7, bid >> 3, hnext, H2_, W_dec, H2_, b_dec, dec, H2_, H2_, 256, 1);
  else
    mb_convert_unit(mb, mbT, (19200 + bid - 32) * 256 + threadIdx.x);
}

// ---------------- scores v10: 128x128 tile, 64x64 wave tiles, BK=32, dbuf in 32KB ----
// 32KB total LDS -> 4-5 blocks/CU (vs 2 at 64KB) for cross-block wave overlap (m114).
// Per K-step (32 steps): issue 4 gl_lds -> buf^1 (per-lane pre-swizzled global src,
// linear LDS dest), vmcnt(4) [never 0 mid-loop], barrier, 8 ds_read + 16 MFMA, barrier.
// LDS image k-major: unit addr = kk*2048 + row*16 (A), +8192 (B).
__launch_bounds__(256)
__global__ void scores_kernel(const unsigned char* __restrict__ mbT,
                              const unsigned char* __restrict__ WTt,
                              const float* __restrict__ dec, const float* __restrict__ vvec,
                              float* __restrict__ scrp)
{
  __shared__ __align__(16) unsigned char LDSm[32768];   // 2 buf x (A 8KB | B 8KB)
  const int tid = threadIdx.x, lane = tid & 63;
  const int wv = tid >> 6, lr = lane & 15, lhi = lane >> 4;
  const int wru = wv >> 1, wcu = wv & 1;   // wave tile: 64 rows x 64 cols

  int p = blockIdx.x;
  int lid = (p & 7) * 400 + (p >> 3);      // bijective: 3200 = 8*400
  int rp = lid >> 3, cp = lid & 7;
  int r0 = rp << 7;

  int wvu = __builtin_amdgcn_readfirstlane(wv);
  const unsigned char* baseA = mbT + (size_t)rp * 262144;
  const unsigned char* baseB = WTt + (size_t)cp * 262144;

  // staging: wave wvu, rounds j=0,1 -> unit uu = wvu*128 + j*64 + lane (512 units/half)
  // chunk-internal src offset for k-half h: ((r*128 + (h*4+kk)*16) ^ ((r&7)<<4))
  int srcOff[2][2];  // [j][h]
  int dstOff[2];     // linear LDS (within half-buffer)
  #pragma unroll
  for (int j = 0; j < 2; j++){
    int uu = wvu * 128 + j * 64 + lane;
    int kk = uu >> 7, r = uu & 127;
    #pragma unroll
    for (int h = 0; h < 2; h++)
      srcOff[j][h] = (r * 128 + (h * 4 + kk) * 16) ^ ((r & 7) << 4);
    dstOff[j] = (wvu * 2 + j) * 1024 + lane * 16;
  }

  // fragment read offsets (k-major image): A: kk*2048 + row*16 ; B: +8192
  int aoff[4], boff[4];
  #pragma unroll
  for (int rf = 0; rf < 4; rf++){
    int row = wru * 64 + rf * 16 + lr;
    aoff[rf] = lhi * 2048 + row * 16;
  }
  #pragma unroll
  for (int cf = 0; cf < 4; cf++){
    int col = wcu * 64 + cf * 16 + lr;
    boff[cf] = 8192 + lhi * 2048 + col * 16;
  }

  f32x4 zero = {0.f, 0.f, 0.f, 0.f};
  f32x4 acc[4][4];
  #pragma unroll
  for (int rf = 0; rf < 4; rf++)
    #pragma unroll
    for (int cf = 0; cf < 4; cf++) acc[rf][cf] = zero;

  // prologue: stage K-step 0 (ks2=0, h=0) into buf 0
  #pragma unroll
  for (int j = 0; j < 2; j++){
    gl_lds16(baseA + srcOff[j][0], &LDSm[dstOff[j]]);
    gl_lds16(baseB + srcOff[j][0], &LDSm[8192 + dstOff[j]]);
  }

  #pragma unroll 1
  for (int t = 0; t < 32; ++t){
    const int cur = (t & 1) << 14;
    if (t < 31){
      const int tn = t + 1;
      const size_t chunk = (size_t)(tn >> 1) * 16384;
      const int h = tn & 1;
      const int nb = (tn & 1) << 14;
      #pragma unroll
      for (int j = 0; j < 2; j++){
        gl_lds16(baseA + chunk + srcOff[j][h], &LDSm[nb + dstOff[j]]);
        gl_lds16(baseB + chunk + srcOff[j][h], &LDSm[nb + 8192 + dstOff[j]]);
      }
      asm volatile("s_waitcnt vmcnt(4)" ::: "memory");
    } else {
      asm volatile("s_waitcnt vmcnt(0)" ::: "memory");
    }
    __builtin_amdgcn_s_barrier();
    __builtin_amdgcn_sched_barrier(0);   // fence: no ds_read hoists above the barrier

    short8 af[4], bfr[4];
    #pragma unroll
    for (int rf = 0; rf < 4; rf++) af[rf]  = *(const short8*)&LDSm[cur + aoff[rf]];
    #pragma unroll
    for (int cf = 0; cf < 4; cf++) bfr[cf] = *(const short8*)&LDSm[cur + boff[cf]];
    #pragma unroll
    for (int rf = 0; rf < 4; rf++)
      #pragma unroll
      for (int cf = 0; cf < 4; cf++)
        acc[rf][cf] = __builtin_amdgcn_mfma_f32_16x16x32_bf16(af[rf], bfr[cf], acc[rf][cf], 0, 0, 0);

    __builtin_amdgcn_sched_barrier(0);   // fence: compute stays above the barrier
    __builtin_amdgcn_s_barrier();
    __builtin_amdgcn_sched_barrier(0);   // fence: next-iter gl_lds stays below
  }

  // fused epilogue: sum_cols tanh(acc + dec) * v -> plain partial store per (row, cp, wcu)
  int colb = (cp << 7) + wcu * 64 + lr;
  float vv0 = vvec[colb], vv1 = vvec[colb + 16], vv2 = vvec[colb + 32], vv3 = vvec[colb + 48];
  #pragma unroll
  for (int rf = 0; rf < 4; rf++){
    #pragma unroll
    for (int i = 0; i < 4; i++){
      int grow = r0 + wru * 64 + rf * 16 + lhi * 4 + i;
      int bb = grow / 400;
      const float* dp = dec + (size_t)bb * 1024 + colb;
      float x0 = acc[rf][0][i] + dp[0];
      float x1 = acc[rf][1][i] + dp[16];
      float x2 = acc[rf][2][i] + dp[32];
      float x3 = acc[rf][3][i] + dp[48];
      float part = (1.f - 2.f / (__expf(2.f * x0) + 1.f)) * vv0
                 + (1.f - 2.f / (__expf(2.f * x1) + 1.f)) * vv1
                 + (1.f - 2.f / (__expf(2.f * x2) + 1.f)) * vv2
                 + (1.f - 2.f / (__expf(2.f * x3) + 1.f)) * vv3;
      part += __shfl_xor(part, 1);
      part += __shfl_xor(part, 2);
      part += __shfl_xor(part, 4);
      part += __shfl_xor(part, 8);
      if (lr == 0) scrp[(size_t)grow * 16 + cp * 2 + wcu] = part;
    }
  }
}

// ---------------- context + fused masked softmax; sums 16 scrp partials per row --------
__launch_bounds__(256)
__global__ void context_kernel(const float* __restrict__ scrp, const float* __restrict__ mask,
                               const unsigned char* __restrict__ mbT,
                               float* __restrict__ ctx, float* __restrict__ attn){
  int b = blockIdx.y, lc = blockIdx.x, t = threadIdx.x;
  int wv = t >> 6, lane = t & 63;
  __shared__ float red[4];
  __shared__ float a[400];
  int row0 = b * 400 + t;
  float s0 = 0.f, s1;
  {
    const float4* p0 = (const float4*)(scrp + (size_t)row0 * 16);
    #pragma unroll
    for (int q = 0; q < 4; q++){ float4 v = p0[q]; s0 += v.x + v.y + v.z + v.w; }
    if (t < 144){
      s1 = 0.f;
      const float4* p1 = (const float4*)(scrp + (size_t)(row0 + 256) * 16);
      #pragma unroll
      for (int q = 0; q < 4; q++){ float4 v = p1[q]; s1 += v.x + v.y + v.z + v.w; }
    } else s1 = -1e30f;
  }
  float m = wredmax(fmaxf(s0, s1));
  if (lane == 0) red[wv] = m;
  __syncthreads();
  float M = fmaxf(fmaxf(red[0], red[1]), fmaxf(red[2], red[3]));
  __syncthreads();
  float e0 = __expf(s0 - M) * mask[b * 400 + t];
  float e1 = (t < 144) ? __expf(s1 - M) * mask[b * 400 + t + 256] : 0.f;
  float s = wredsum(e0 + e1);
  if (lane == 0) red[wv] = s;
  __syncthreads();
  float inv = 1.f / (red[0] + red[1] + red[2] + red[3]);
  a[t] = e0 * inv;
  if (t < 144) a[t + 256] = e1 * inv;
  __syncthreads();
  if (t < 100) attn[b * 400 + lc * 100 + t] = a[lc * 100 + t];

  int u = t & 127;            // 16B unit (8 m-values)
  int half = t >> 7;
  int ks = u >> 3, c16 = u & 7;
  float sa[8];
  #pragma unroll
  for (int j = 0; j < 8; j++) sa[j] = 0.f;
  for (int l = half; l < 100; l += 2){
    int gr = b * 400 + lc * 100 + l;
    int panel = gr >> 7, r = gr & 127;
    const unsigned char* pp = mbT + (size_t)panel * 262144 + (size_t)ks * 16384
                              + (size_t)((r * 128 + c16 * 16) ^ ((r & 7) << 4));
    short8 v = *(const short8*)pp;
    float al = a[lc * 100 + l];
    #pragma unroll
    for (int j = 0; j < 8; j++) sa[j] += al * bf2f((unsigned short)v[j]);
  }
  float* cp = ctx + (size_t)b * M_ + u * 8;
  #pragma unroll
  for (int j = 0; j < 8; j++) atomicAdd(cp + j, sa[j]);
}

// ---------------- v1 GEMM (64 blocks -> partials, plain stores) + pgen (128 blocks) ----------------
__launch_bounds__(256)
__global__ void v1_pgen_kernel(const float* __restrict__ ctx, const float* __restrict__ hn,
                               const float* __restrict__ yemb,
                               const float* __restrict__ Wv1, const float* __restrict__ bv1,
                               float* __restrict__ vp,
                               const float* __restrict__ Wp, const float* __restrict__ bp,
                               float* __restrict__ pg)
{
  int bid = blockIdx.x;
  if (bid < 64){
    int bx = bid & 7, by = bid >> 3;
    int tid = threadIdx.x;
    int wv = tid >> 6, lane = tid & 63, lr = lane & 15, lhi = lane >> 4;
    int colBase = bx * 128 + wv * 32;
    const float* Asrc = (by < 4) ? ctx : hn;
    int k0 = ((by < 4) ? by : (by - 4)) * 256;
    int wk0 = by * 256;

    f32x4 zero = {0.f, 0.f, 0.f, 0.f};
    f32x4 acc[8][2];
    #pragma unroll
    for (int r = 0; r < 8; r++){ acc[r][0] = zero; acc[r][1] = zero; }

    for (int ks = 0; ks < 8; ++ks){
      int k  = k0 + ks * 32 + lhi * 8;
      int wk = wk0 + ks * 32 + lhi * 8;
      short8 bf[2];
      #pragma unroll
      for (int cf = 0; cf < 2; cf++){
        #pragma unroll
        for (int j = 0; j < 8; j++)
          bf[cf][j] = (short)f2bf(Wv1[(size_t)(wk + j) * H2_ + colBase + cf * 16 + lr]);
      }
      #pragma unroll
      for (int rf = 0; rf < 8; rf++){
        const float* ap = Asrc + (size_t)(rf * 16 + lr) * 1024 + k;
        float4 a0 = *(const float4*)ap;
        float4 a1 = *(const float4*)(ap + 4);
        short8 af;
        af[0]=(short)f2bf(a0.x); af[1]=(short)f2bf(a0.y); af[2]=(short)f2bf(a0.z); af[3]=(short)f2bf(a0.w);
        af[4]=(short)f2bf(a1.x); af[5]=(short)f2bf(a1.y); af[6]=(short)f2bf(a1.z); af[7]=(short)f2bf(a1.w);
        acc[rf][0] = __builtin_amdgcn_mfma_f32_16x16x32_bf16(af, bf[0], acc[rf][0], 0, 0, 0);
        acc[rf][1] = __builtin_amdgcn_mfma_f32_16x16x32_bf16(af, bf[1], acc[rf][1], 0, 0, 0);
      }
    }

    float* Cw = vp + (size_t)by * 131072;
    bool addB = (by == 0);
    #pragma unroll
    for (int cf = 0; cf < 2; cf++){
      int col = colBase + cf * 16 + lr;
      float bv = addB ? bv1[col] : 0.f;
      #pragma unroll
      for (int rf = 0; rf < 8; rf++)
        #pragma unroll
        for (int i = 0; i < 4; i++){
          int row = rf * 16 + lhi * 4 + i;
          Cw[(size_t)row * H2_ + col] = acc[rf][cf][i] + bv;
        }
    }
  } else {
    int b = bid - 64, t = threadIdx.x, wv = t >> 6, lane = t & 63;
    __shared__ float red[4];
    float s = 0.f;
    for (int i = t; i < 1024; i += 256) s += ctx[(size_t)b * 1024 + i] * Wp[i];
    for (int i = t; i < 1024; i += 256) s += hn[(size_t)b * 1024 + i] * Wp[1024 + i];
    for (int i = t; i < 512;  i += 256) s += yemb[(size_t)b * 512 + i] * Wp[2048 + i];
    s = wredsum(s);
    if (lane == 0) red[wv] = s;
    __syncthreads();
    if (t == 0){
      float S = red[0] + red[1] + red[2] + red[3] + bp[0];
      pg[b] = 1.f / (1.f + __expf(-S));
    }
  }
}

// ---------------- sum v1 partials -> bf16 hid ----------------
__global__ void hid2bf_kernel(const float* __restrict__ vp, unsigned short* __restrict__ hb){
  int id = blockIdx.x * 256 + threadIdx.x;   // 32768 float4-groups
  float4 s = *(const float4*)(vp + (size_t)id * 4);
  #pragma unroll
  for (int ky = 1; ky < 8; ky++){
    float4 v = *(const float4*)(vp + (size_t)ky * 131072 + (size_t)id * 4);
    s.x += v.x; s.y += v.y; s.z += v.z; s.w += v.w;
  }
  ushort2 p0 = {f2bf(s.x), f2bf(s.y)};
  ushort2 p1 = {f2bf(s.z), f2bf(s.w)};
  *(ushort2*)(hb + (size_t)id * 4)     = p0;
  *(ushort2*)(hb + (size_t)id * 4 + 2) = p1;
}

// ---------------- logits GEMM: bf16 A, fp32 W, 64-col tiles (782 blocks, ~3/CU) ----------------
__launch_bounds__(256)
__global__ void gemm_bfA_kernel(const unsigned short* __restrict__ A,
                                const float* __restrict__ W,
                                const float* __restrict__ bias,
                                float* __restrict__ C, int N)
{
  int tid = threadIdx.x;
  int wv = tid >> 6, lane = tid & 63, lr = lane & 15, lhi = lane >> 4;
  int colBase = blockIdx.x * 64 + wv * 16;
  int colL = min(colBase + lr, N - 1);

  f32x4 zero = {0.f, 0.f, 0.f, 0.f};
  f32x4 acc[8];
  #pragma unroll
  for (int r = 0; r < 8; r++) acc[r] = zero;

  for (int ks = 0; ks < 32; ++ks){
    int k = ks * 32 + lhi * 8;
    short8 bf;
    #pragma unroll
    for (int j = 0; j < 8; j++)
      bf[j] = f2bf_t(W[(size_t)(k + j) * N + colL]);
    #pragma unroll
    for (int rf = 0; rf < 8; rf++){
      short8 af = *(const short8*)(A + (size_t)(rf * 16 + lr) * 1024 + k);
      acc[rf] = __builtin_amdgcn_mfma_f32_16x16x32_bf16(af, bf, acc[rf], 0, 0, 0);
    }
  }

  int col = colBase + lr;
  bool ok = col < N;
  float bv = bias[colL];
  #pragma unroll
  for (int rf = 0; rf < 8; rf++)
    #pragma unroll
    for (int i = 0; i < 4; i++){
      int row = rf * 16 + lhi * 4 + i;
      if (ok) C[(size_t)row * V_ + col] = acc[rf][i] + bv;
    }
}

// ---------------- vocab softmax (online, no store-back) + p_gen scale + fused scatter ----------------
__global__ void vocab_softmax_kernel(const float* __restrict__ lg0, const float* __restrict__ pg,
                                     const float* __restrict__ attn, const int* __restrict__ soov,
                                     float* __restrict__ fin){
  int b = blockIdx.x, t = threadIdx.x, wv = t >> 6, lane = t & 63;
  __shared__ float redm[16], reds[16];
  const float* l0 = lg0 + (size_t)b * V_;
  float m = -1e30f, s = 0.f;
  for (int i = t; i < V_; i += 1024){
    float l = l0[i];
    float mn = fmaxf(m, l);
    s = s * __expf(m - mn) + __expf(l - mn);
    m = mn;
  }
  #pragma unroll
  for (int o = 32; o > 0; o >>= 1){
    float mo = __shfl_xor(m, o), so = __shfl_xor(s, o);
    float mn = fmaxf(m, mo);
    s = s * __expf(m - mn) + so * __expf(mo - mn);
    m = mn;
  }
  if (lane == 0){ redm[wv] = m; reds[wv] = s; }
  __syncthreads();
  float M = -1e30f;
  #pragma unroll
  for (int w = 0; w < 16; w++) M = fmaxf(M, redm[w]);
  float S = 0.f;
  #pragma unroll
  for (int w = 0; w < 16; w++) S += reds[w] * __expf(redm[w] - M);
  float pgb = pg[b];
  float scale = pgb / S;
  float* fb = fin + (size_t)b * VE_;
  for (int i = t; i < V_; i += 1024) fb[i] = __expf(l0[i] - M) * scale;
  for (int i = V_ + t; i < VE_; i += 1024) fb[i] = 0.f;
  __syncthreads();
  float om = 1.f - pgb;
  if (t < 400) atomicAdd(&fb[soov[b * 400 + t]], om * attn[b * 400 + t]);
}

extern "C" void kernel_launch(void* const* d_in, const int* in_sizes, int n_in,
                              void* d_out, int out_size, void* d_ws, size_t ws_size,
                              hipStream_t stream)
{
  const int*   y     = (const int*)  d_in[0];
  const float* hin   = (const float*)d_in[1];
  const float* mb    = (const float*)d_in[2];
  const float* mask  = (const float*)d_in[3];
  const int*   soov  = (const int*)  d_in[5];
  const float* emb   = (const float*)d_in[6];
  const float* W_ih  = (const float*)d_in[7];
  const float* W_hh  = (const float*)d_in[8];
  const float* b_ih  = (const float*)d_in[9];
  const float* b_hh  = (const float*)d_in[10];
  const float* W_mem = (const float*)d_in[11];
  const float* W_dec = (const float*)d_in[12];
  const float* b_dec = (const float*)d_in[13];
  const float* vvec  = (const float*)d_in[14];
  const float* W_pg  = (const float*)d_in[15];
  const float* b_pg  = (const float*)d_in[16];
  const float* W_v1  = (const float*)d_in[17];
  const float* b_v1  = (const float*)d_in[18];
  const float* W_v2  = (const float*)d_in[19];
  const float* b_v2  = (const float*)d_in[20];

  float* out   = (float*)d_out;
  float* fin   = out;                               // [128, 50050]
  float* hnext = out + (size_t)B_ * VE_;            // [1,128,1024]
  float* ctx   = hnext + (size_t)B_ * H2_;          // [128,1024]
  float* attn  = ctx + (size_t)B_ * M_;             // [128,400]
  float* pg    = attn + (size_t)B_ * L_;            // [128]

  // workspace layout (floats); gi..dec contiguous for one-shot zeroing
  float* ws   = (float*)d_ws;
  float* yemb = ws;                                 //    65536
  float* gi   = ws + 65536;                         //   393216
  float* gh   = gi + 393216;                        //   393216
  float* dec  = gh + 393216;                        //   131072  (gi..dec = 917,504 f)
  float* scrp = dec + 131072;                       //   819200  (51200 rows x 16 partials)
  float* lg0  = scrp + 819200;                      //  6400000
  float* vp   = lg0;                                // v1 partials alias lg0 (consumed pre-logits)
  unsigned short* hidbf = (unsigned short*)(lg0 + 6400000);   // 262144 B
  unsigned char*  WTt   = (unsigned char*)(hidbf + 131072);   // 2 MB
  unsigned char*  mbT   = WTt + 2097152;                      // 100 MB

  // pre: cvt[0,6400) | wmem | embed | zero(gi..dec) | zero(ctx)
  pre_kernel<<<8512, 256, 0, stream>>>(mb, mbT, W_mem, WTt, y, emb, yemb, gi, ctx);
  // gi+gh GEMMs + cvt[6400,12800)
  gigh_kernel<<<6544, 256, 0, stream>>>(yemb, hin, W_ih, W_hh, gi, gh, mb, mbT);
  // GRU gates + cvt[12800,19200)
  gru_gates_kernel<<<6912, 256, 0, stream>>>(gi, gh, b_ih, b_hh, hin, hnext, mb, mbT);
  // dec GEMM + cvt[19200,25600)
  dec_kernel<<<6432, 256, 0, stream>>>(hnext, W_dec, b_dec, dec, mb, mbT);

  scores_kernel<<<3200, 256, 0, stream>>>(mbT, WTt, dec, vvec, scrp);
  context_kernel<<<dim3(4, 128), 256, 0, stream>>>(scrp, mask, mbT, ctx, attn);

  v1_pgen_kernel<<<192, 256, 0, stream>>>(ctx, hnext, yemb, W_v1, b_v1, vp, W_pg, b_pg, pg);
  hid2bf_kernel<<<128, 256, 0, stream>>>(vp, hidbf);
  gemm_bfA_kernel<<<782, 256, 0, stream>>>(hidbf, W_v2, b_v2, lg0, V_);

  vocab_softmax_kernel<<<128, 1024, 0, stream>>>(lg0, pg, attn, soov, fin);
}

// Round 15
// 503.356 us; speedup vs baseline: 1.1380x; 1.1380x over previous
//
#include <hip/hip_runtime.h>

#define B_   128
#define L_   400
#define V_   50000
#define E_   512
#define H2_  1024
#define M_   1024
#define OOV_ 50
#define VE_  50050   // V + OOV
#define BL_  51200   // B*L

typedef __attribute__((ext_vector_type(8))) short short8;
typedef __attribute__((ext_vector_type(4))) float f32x4;

__device__ __forceinline__ unsigned short f2bf(float f){
  unsigned int u = __builtin_bit_cast(unsigned int, f);
  u = (u + 0x7FFFu + ((u >> 16) & 1u)) >> 16;
  return (unsigned short)u;
}
__device__ __forceinline__ float bf2f(unsigned short s){
  unsigned int u = ((unsigned int)s) << 16;
  return __builtin_bit_cast(float, u);
}
// truncating fp32->bf16 (1 VALU op)
__device__ __forceinline__ short f2bf_t(float f){
  return (short)(__builtin_bit_cast(unsigned int, f) >> 16);
}

__device__ __forceinline__ void gl_lds16(const void* g, void* l){
  __builtin_amdgcn_global_load_lds(
      (const __attribute__((address_space(1))) unsigned int*)g,
      (__attribute__((address_space(3))) unsigned int*)l, 16, 0, 0);
}

__device__ __forceinline__ float wredsum(float v){
  #pragma unroll
  for (int o = 32; o > 0; o >>= 1) v += __shfl_xor(v, o);
  return v;
}
__device__ __forceinline__ float wredmax(float v){
  #pragma unroll
  for (int o = 32; o > 0; o >>= 1) v = fmaxf(v, __shfl_xor(v, o));
  return v;
}

// ---- mb fp32 [51200][1024] -> tiled+swizzled bf16; one 16B-unit per thread ----
__device__ __forceinline__ void mb_convert_unit(const float* __restrict__ mb,
                                                unsigned char* __restrict__ mbT, int u){
  int gr  = u >> 7;
  int m16 = u & 127;
  const float* src = mb + (size_t)gr * 1024 + m16 * 8;
  float4 f0 = *(const float4*)src;
  float4 f1 = *(const float4*)(src + 4);
  uint4 w;
  w.x = (unsigned)f2bf(f0.x) | ((unsigned)f2bf(f0.y) << 16);
  w.y = (unsigned)f2bf(f0.z) | ((unsigned)f2bf(f0.w) << 16);
  w.z = (unsigned)f2bf(f1.x) | ((unsigned)f2bf(f1.y) << 16);
  w.w = (unsigned)f2bf(f1.z) | ((unsigned)f2bf(f1.w) << 16);
  int panel = gr >> 7, r = gr & 127;
  int ks = m16 >> 3, c16 = m16 & 7;
  size_t dst = (size_t)panel * 262144 + (size_t)ks * 16384
             + (size_t)((r * 128 + c16 * 16) ^ ((r & 7) << 4));
  *(uint4*)(mbT + dst) = w;
}

// ---------------- pre: cvt share | W_mem transpose | embed gather | zeroing ----------------
__global__ void pre_kernel(const float* __restrict__ mb, unsigned char* __restrict__ mbT,
                           const float* __restrict__ Wm, unsigned char* __restrict__ WTt,
                           const int* __restrict__ y, const float* __restrict__ emb,
                           float* __restrict__ yemb, float* __restrict__ zeroA,
                           float* __restrict__ ctx)
{
  __shared__ float tile[32][33];
  int bid = blockIdx.x, t = threadIdx.x;
  if (bid < 6400){                          // convert share [0, 6400)
    mb_convert_unit(mb, mbT, bid * 256 + t);
  } else if (bid < 7424){                   // W_mem [k][n] -> WTt (cols as rows)
    int b2 = bid - 6400;
    int n0 = (b2 & 31) * 32, k0 = (b2 >> 5) * 32;
    int tx = t & 31, ty = t >> 5;
    #pragma unroll
    for (int i = 0; i < 32; i += 8) tile[ty + i][tx] = Wm[(size_t)(k0 + ty + i) * H2_ + n0 + tx];
    __syncthreads();
    if (t < 128){
      int nn = t & 31, k16 = t >> 5;
      int col = n0 + nn, kb = k0 + k16 * 8;
      uint4 w;
      w.x = (unsigned)f2bf(tile[k16*8+0][nn]) | ((unsigned)f2bf(tile[k16*8+1][nn]) << 16);
      w.y = (unsigned)f2bf(tile[k16*8+2][nn]) | ((unsigned)f2bf(tile[k16*8+3][nn]) << 16);
      w.z = (unsigned)f2bf(tile[k16*8+4][nn]) | ((unsigned)f2bf(tile[k16*8+5][nn]) << 16);
      w.w = (unsigned)f2bf(tile[k16*8+6][nn]) | ((unsigned)f2bf(tile[k16*8+7][nn]) << 16);
      int cpn = col >> 7, r = col & 127;
      int ks = kb >> 6, c16 = (kb & 63) >> 3;
      size_t dst = (size_t)cpn * 262144 + (size_t)ks * 16384
                 + (size_t)((r * 128 + c16 * 16) ^ ((r & 7) << 4));
      *(uint4*)(WTt + dst) = w;
    }
  } else if (bid < 7488){                   // embed gather
    int idx = (bid - 7424) * 256 + t;
    int b  = idx >> 7;
    int c4 = (idx & 127) << 2;
    float4 v = *(const float4*)(emb + (size_t)y[b] * E_ + c4);
    *(float4*)(yemb + (size_t)b * E_ + c4) = v;
  } else if (bid < 8434){                   // zero gi|gh|dec|scr (968,704 floats = 946 blocks)
    int u = (bid - 7488) * 256 + t;
    float4 z = {0.f, 0.f, 0.f, 0.f};
    *(float4*)(zeroA + (size_t)u * 4) = z;
  } else {                                  // zero ctx (131,072 floats = 128 blocks)
    int u = (bid - 8434) * 256 + t;
    float4 z = {0.f, 0.f, 0.f, 0.f};
    *(float4*)(ctx + (size_t)u * 4) = z;
  }
}

// ---------------- generic C[128,N] += A[128,K] @ W[K,N] (+bias), fp32 A, atomicAdd ----------------
__device__ __forceinline__ void gemm128_body(int bx, int by,
                               const float* __restrict__ A, int lda,
                               const float* __restrict__ W, int ldw,
                               const float* __restrict__ bias,
                               float* __restrict__ C, int ldc,
                               int N, int kChunk, int addBias)
{
  int tid = threadIdx.x;
  int wv = tid >> 6, lane = tid & 63, lr = lane & 15, lhi = lane >> 4;
  int colBase = bx * 128 + wv * 32;
  int colL[2];
  colL[0] = min(colBase + lr, N - 1);
  colL[1] = min(colBase + 16 + lr, N - 1);
  int k0 = by * kChunk;

  f32x4 zero = {0.f, 0.f, 0.f, 0.f};
  f32x4 acc[8][2];
  #pragma unroll
  for (int r = 0; r < 8; r++){ acc[r][0] = zero; acc[r][1] = zero; }

  int nks = kChunk >> 5;
  for (int ks = 0; ks < nks; ++ks){
    int k = k0 + ks * 32 + lhi * 8;
    short8 bf[2];
    #pragma unroll
    for (int cf = 0; cf < 2; cf++){
      #pragma unroll
      for (int j = 0; j < 8; j++)
        bf[cf][j] = (short)f2bf(W[(size_t)(k + j) * ldw + colL[cf]]);
    }
    #pragma unroll
    for (int rf = 0; rf < 8; rf++){
      const float* ap = A + (size_t)(rf * 16 + lr) * lda + k;
      float4 a0 = *(const float4*)ap;
      float4 a1 = *(const float4*)(ap + 4);
      short8 af;
      af[0]=(short)f2bf(a0.x); af[1]=(short)f2bf(a0.y); af[2]=(short)f2bf(a0.z); af[3]=(short)f2bf(a0.w);
      af[4]=(short)f2bf(a1.x); af[5]=(short)f2bf(a1.y); af[6]=(short)f2bf(a1.z); af[7]=(short)f2bf(a1.w);
      acc[rf][0] = __builtin_amdgcn_mfma_f32_16x16x32_bf16(af, bf[0], acc[rf][0], 0, 0, 0);
      acc[rf][1] = __builtin_amdgcn_mfma_f32_16x16x32_bf16(af, bf[1], acc[rf][1], 0, 0, 0);
    }
  }

  bool addB = addBias && (by == 0);
  #pragma unroll
  for (int cf = 0; cf < 2; cf++){
    int col = colBase + cf * 16 + lr;
    bool ok = col < N;
    float bv = addB ? bias[colL[cf]] : 0.f;
    #pragma unroll
    for (int rf = 0; rf < 8; rf++)
      #pragma unroll
      for (int i = 0; i < 4; i++){
        int row = rf * 16 + lhi * 4 + i;
        if (ok) atomicAdd(&C[(size_t)row * ldc + col], acc[rf][cf][i] + bv);
      }
  }
}

// gi (48 blocks) + gh (96 blocks) + convert share [6400, 12800)
__launch_bounds__(256)
__global__ void gigh_kernel(const float* __restrict__ yemb, const float* __restrict__ hin,
                            const float* __restrict__ W_ih, const float* __restrict__ W_hh,
                            float* __restrict__ gi, float* __restrict__ gh,
                            const float* __restrict__ mb, unsigned char* __restrict__ mbT){
  int bid = blockIdx.x;
  if (bid < 48)
    gemm128_body(bid % 24, bid / 24, yemb, E_,  W_ih, 3 * H2_, nullptr, gi, 3 * H2_, 3 * H2_, 256, 0);
  else if (bid < 144){
    int b2 = bid - 48;
    gemm128_body(b2 % 24, b2 / 24, hin, H2_, W_hh, 3 * H2_, nullptr, gh, 3 * H2_, 3 * H2_, 256, 0);
  } else {
    mb_convert_unit(mb, mbT, (6400 + bid - 144) * 256 + threadIdx.x);
  }
}

// ---------------- GRU gates (512 blocks) + convert share [12800, 19200) ----------------
__global__ void gru_gates_kernel(const float* __restrict__ gi, const float* __restrict__ gh,
                                 const float* __restrict__ bih, const float* __restrict__ bhh,
                                 const float* __restrict__ h0, float* __restrict__ hn,
                                 const float* __restrict__ mb, unsigned char* __restrict__ mbT){
  int bid = blockIdx.x;
  if (bid >= 512){
    mb_convert_unit(mb, mbT, (12800 + bid - 512) * 256 + threadIdx.x);
    return;
  }
  int idx = bid * 256 + threadIdx.x;
  int b = idx >> 10, j = idx & 1023;
  const float* gib = gi + (size_t)b * 3072;
  const float* ghb = gh + (size_t)b * 3072;
  float ir = gib[j]        + bih[j],        hr = ghb[j]        + bhh[j];
  float iz = gib[j + 1024] + bih[j + 1024], hz = ghb[j + 1024] + bhh[j + 1024];
  float in_= gib[j + 2048] + bih[j + 2048], hnv= ghb[j + 2048] + bhh[j + 2048];
  float r = 1.f / (1.f + __expf(-(ir + hr)));
  float z = 1.f / (1.f + __expf(-(iz + hz)));
  float n = tanhf(in_ + r * hnv);
  hn[idx] = (1.f - z) * n + z * h0[idx];
}

// dec GEMM (32 blocks) + convert share [19200, 25600)
__launch_bounds__(256)
__global__ void dec_kernel(const float* __restrict__ hnext, const float* __restrict__ W_dec,
                           const float* __restrict__ b_dec, float* __restrict__ dec,
                           const float* __restrict__ mb, unsigned char* __restrict__ mbT){
  int bid = blockIdx.x;
  if (bid < 32)
    gemm128_body(bid & 7, bid >> 3, hnext, H2_, W_dec, H2_, b_dec, dec, H2_, H2_, 256, 1);
  else
    mb_convert_unit(mb, mbT, (19200 + bid - 32) * 256 + threadIdx.x);
}

// ---------------- scores (proven R8): 128x128 tile, 64x64 wave tiles, dbuf gl_lds ----
// Counted vmcnt(8) [never 0 mid-loop] + raw barriers; compiler freely interleaves
// ds_read with MFMA inside the compute region. Epilogue: atomicAdd into scr.
__launch_bounds__(256)
__global__ void scores_kernel(const unsigned char* __restrict__ mbT,
                              const unsigned char* __restrict__ WTt,
                              const float* __restrict__ dec, const float* __restrict__ vvec,
                              float* __restrict__ scr)
{
  __shared__ __align__(16) unsigned char LDSm[65536];   // 2 x (A 16KB | B 16KB)
  const int tid = threadIdx.x, lane = tid & 63;
  const int wv = tid >> 6, lr = lane & 15, lhi = lane >> 4;
  const int wru = wv >> 1, wcu = wv & 1;   // wave tile: 64 rows x 64 cols

  int p = blockIdx.x;
  int lid = (p & 7) * 400 + (p >> 3);      // bijective: 3200 = 8*400
  int rp = lid >> 3, cp = lid & 7;
  int r0 = rp << 7;

  int wvu = __builtin_amdgcn_readfirstlane(wv);
  const unsigned char* segA = mbT + (size_t)rp * 262144 + wvu * 4096 + lane * 16;
  const unsigned char* segB = WTt + (size_t)cp * 262144 + wvu * 4096 + lane * 16;
  const int ldsA = wvu * 4096;
  const int ldsB = 16384 + wvu * 4096;

  int aoff[4], boff[4];
  #pragma unroll
  for (int rf = 0; rf < 4; rf++){
    int row = wru * 64 + rf * 16 + lr;
    aoff[rf] = (row * 128 + lhi * 16) ^ ((row & 7) << 4);
  }
  #pragma unroll
  for (int cf = 0; cf < 4; cf++){
    int col = wcu * 64 + cf * 16 + lr;
    boff[cf] = ((col * 128 + lhi * 16) ^ ((col & 7) << 4)) + 16384;
  }

  f32x4 zero = {0.f, 0.f, 0.f, 0.f};
  f32x4 acc[4][4];
  #pragma unroll
  for (int rf = 0; rf < 4; rf++)
    #pragma unroll
    for (int cf = 0; cf < 4; cf++) acc[rf][cf] = zero;

  // prologue: stage K-tile 0 into buf 0
  #pragma unroll
  for (int j = 0; j < 4; j++){
    gl_lds16(segA + j * 1024, &LDSm[ldsA + j * 1024]);
    gl_lds16(segB + j * 1024, &LDSm[ldsB + j * 1024]);
  }

  #pragma unroll 1
  for (int t = 0; t < 16; ++t){
    const int cur = (t & 1) << 15;
    if (t < 15){
      const size_t soff = (size_t)(t + 1) * 16384;
      const int nb = ((t + 1) & 1) << 15;
      #pragma unroll
      for (int j = 0; j < 4; j++){
        gl_lds16(segA + soff + j * 1024, &LDSm[nb + ldsA + j * 1024]);
        gl_lds16(segB + soff + j * 1024, &LDSm[nb + ldsB + j * 1024]);
      }
      asm volatile("s_waitcnt vmcnt(8)" ::: "memory");
    } else {
      asm volatile("s_waitcnt vmcnt(0)" ::: "memory");
    }
    __builtin_amdgcn_s_barrier();
    __builtin_amdgcn_sched_barrier(0);   // fence: no ds_read hoists above the barrier

    #pragma unroll
    for (int k2 = 0; k2 < 2; k2++){
      short8 af[4], bfr[4];
      #pragma unroll
      for (int rf = 0; rf < 4; rf++) af[rf]  = *(const short8*)&LDSm[cur + (aoff[rf] ^ (k2 << 6))];
      #pragma unroll
      for (int cf = 0; cf < 4; cf++) bfr[cf] = *(const short8*)&LDSm[cur + (boff[cf] ^ (k2 << 6))];
      #pragma unroll
      for (int rf = 0; rf < 4; rf++)
        #pragma unroll
        for (int cf = 0; cf < 4; cf++)
          acc[rf][cf] = __builtin_amdgcn_mfma_f32_16x16x32_bf16(af[rf], bfr[cf], acc[rf][cf], 0, 0, 0);
    }

    __builtin_amdgcn_sched_barrier(0);   // fence: compute stays above the barrier
    __builtin_amdgcn_s_barrier();
    __builtin_amdgcn_sched_barrier(0);   // fence: next-iter gl_lds stays below
  }

  // fused epilogue: sum_cols tanh(acc + dec) * v -> atomicAdd per row
  int colb = (cp << 7) + wcu * 64 + lr;
  float vv0 = vvec[colb], vv1 = vvec[colb + 16], vv2 = vvec[colb + 32], vv3 = vvec[colb + 48];
  #pragma unroll
  for (int rf = 0; rf < 4; rf++){
    #pragma unroll
    for (int i = 0; i < 4; i++){
      int grow = r0 + wru * 64 + rf * 16 + lhi * 4 + i;
      int bb = grow / 400;
      const float* dp = dec + (size_t)bb * 1024 + colb;
      float x0 = acc[rf][0][i] + dp[0];
      float x1 = acc[rf][1][i] + dp[16];
      float x2 = acc[rf][2][i] + dp[32];
      float x3 = acc[rf][3][i] + dp[48];
      float part = (1.f - 2.f / (__expf(2.f * x0) + 1.f)) * vv0
                 + (1.f - 2.f / (__expf(2.f * x1) + 1.f)) * vv1
                 + (1.f - 2.f / (__expf(2.f * x2) + 1.f)) * vv2
                 + (1.f - 2.f / (__expf(2.f * x3) + 1.f)) * vv3;
      part += __shfl_xor(part, 1);
      part += __shfl_xor(part, 2);
      part += __shfl_xor(part, 4);
      part += __shfl_xor(part, 8);
      if (lr == 0) atomicAdd(&scr[grow], part);
    }
  }
}

// ---------------- context + fused masked softmax (each block recomputes softmax) ----------------
__launch_bounds__(256)
__global__ void context_kernel(const float* __restrict__ scr, const float* __restrict__ mask,
                               const unsigned char* __restrict__ mbT,
                               float* __restrict__ ctx, float* __restrict__ attn){
  int b = blockIdx.y, lc = blockIdx.x, t = threadIdx.x;
  int wv = t >> 6, lane = t & 63;
  __shared__ float red[4];
  __shared__ float a[400];
  float s0 = scr[b * 400 + t];
  float s1 = (t < 144) ? scr[b * 400 + t + 256] : -1e30f;
  float m = wredmax(fmaxf(s0, s1));
  if (lane == 0) red[wv] = m;
  __syncthreads();
  float M = fmaxf(fmaxf(red[0], red[1]), fmaxf(red[2], red[3]));
  __syncthreads();
  float e0 = __expf(s0 - M) * mask[b * 400 + t];
  float e1 = (t < 144) ? __expf(s1 - M) * mask[b * 400 + t + 256] : 0.f;
  float s = wredsum(e0 + e1);
  if (lane == 0) red[wv] = s;
  __syncthreads();
  float inv = 1.f / (red[0] + red[1] + red[2] + red[3]);
  a[t] = e0 * inv;
  if (t < 144) a[t + 256] = e1 * inv;
  __syncthreads();
  if (t < 100) attn[b * 400 + lc * 100 + t] = a[lc * 100 + t];

  int u = t & 127;            // 16B unit (8 m-values)
  int half = t >> 7;
  int ks = u >> 3, c16 = u & 7;
  float sa[8];
  #pragma unroll
  for (int j = 0; j < 8; j++) sa[j] = 0.f;
  for (int l = half; l < 100; l += 2){
    int gr = b * 400 + lc * 100 + l;
    int panel = gr >> 7, r = gr & 127;
    const unsigned char* pp = mbT + (size_t)panel * 262144 + (size_t)ks * 16384
                              + (size_t)((r * 128 + c16 * 16) ^ ((r & 7) << 4));
    short8 v = *(const short8*)pp;
    float al = a[lc * 100 + l];
    #pragma unroll
    for (int j = 0; j < 8; j++) sa[j] += al * bf2f((unsigned short)v[j]);
  }
  float* cp = ctx + (size_t)b * M_ + u * 8;
  #pragma unroll
  for (int j = 0; j < 8; j++) atomicAdd(cp + j, sa[j]);
}

// ---------------- v1 GEMM (64 blocks -> partials, plain stores) + pgen (128 blocks) ----------------
__launch_bounds__(256)
__global__ void v1_pgen_kernel(const float* __restrict__ ctx, const float* __restrict__ hn,
                               const float* __restrict__ yemb,
                               const float* __restrict__ Wv1, const float* __restrict__ bv1,
                               float* __restrict__ vp,
                               const float* __restrict__ Wp, const float* __restrict__ bp,
                               float* __restrict__ pg)
{
  int bid = blockIdx.x;
  if (bid < 64){
    int bx = bid & 7, by = bid >> 3;
    int tid = threadIdx.x;
    int wv = tid >> 6, lane = tid & 63, lr = lane & 15, lhi = lane >> 4;
    int colBase = bx * 128 + wv * 32;
    const float* Asrc = (by < 4) ? ctx : hn;
    int k0 = ((by < 4) ? by : (by - 4)) * 256;
    int wk0 = by * 256;

    f32x4 zero = {0.f, 0.f, 0.f, 0.f};
    f32x4 acc[8][2];
    #pragma unroll
    for (int r = 0; r < 8; r++){ acc[r][0] = zero; acc[r][1] = zero; }

    for (int ks = 0; ks < 8; ++ks){
      int k  = k0 + ks * 32 + lhi * 8;
      int wk = wk0 + ks * 32 + lhi * 8;
      short8 bf[2];
      #pragma unroll
      for (int cf = 0; cf < 2; cf++){
        #pragma unroll
        for (int j = 0; j < 8; j++)
          bf[cf][j] = (short)f2bf(Wv1[(size_t)(wk + j) * H2_ + colBase + cf * 16 + lr]);
      }
      #pragma unroll
      for (int rf = 0; rf < 8; rf++){
        const float* ap = Asrc + (size_t)(rf * 16 + lr) * 1024 + k;
        float4 a0 = *(const float4*)ap;
        float4 a1 = *(const float4*)(ap + 4);
        short8 af;
        af[0]=(short)f2bf(a0.x); af[1]=(short)f2bf(a0.y); af[2]=(short)f2bf(a0.z); af[3]=(short)f2bf(a0.w);
        af[4]=(short)f2bf(a1.x); af[5]=(short)f2bf(a1.y); af[6]=(short)f2bf(a1.z); af[7]=(short)f2bf(a1.w);
        acc[rf][0] = __builtin_amdgcn_mfma_f32_16x16x32_bf16(af, bf[0], acc[rf][0], 0, 0, 0);
        acc[rf][1] = __builtin_amdgcn_mfma_f32_16x16x32_bf16(af, bf[1], acc[rf][1], 0, 0, 0);
      }
    }

    float* Cw = vp + (size_t)by * 131072;
    bool addB = (by == 0);
    #pragma unroll
    for (int cf = 0; cf < 2; cf++){
      int col = colBase + cf * 16 + lr;
      float bv = addB ? bv1[col] : 0.f;
      #pragma unroll
      for (int rf = 0; rf < 8; rf++)
        #pragma unroll
        for (int i = 0; i < 4; i++){
          int row = rf * 16 + lhi * 4 + i;
          Cw[(size_t)row * H2_ + col] = acc[rf][cf][i] + bv;
        }
    }
  } else {
    int b = bid - 64, t = threadIdx.x, wv = t >> 6, lane = t & 63;
    __shared__ float red[4];
    float s = 0.f;
    for (int i = t; i < 1024; i += 256) s += ctx[(size_t)b * 1024 + i] * Wp[i];
    for (int i = t; i < 1024; i += 256) s += hn[(size_t)b * 1024 + i] * Wp[1024 + i];
    for (int i = t; i < 512;  i += 256) s += yemb[(size_t)b * 512 + i] * Wp[2048 + i];
    s = wredsum(s);
    if (lane == 0) red[wv] = s;
    __syncthreads();
    if (t == 0){
      float S = red[0] + red[1] + red[2] + red[3] + bp[0];
      pg[b] = 1.f / (1.f + __expf(-S));
    }
  }
}

// ---------------- sum v1 partials -> bf16 hid ----------------
__global__ void hid2bf_kernel(const float* __restrict__ vp, unsigned short* __restrict__ hb){
  int id = blockIdx.x * 256 + threadIdx.x;   // 32768 float4-groups
  float4 s = *(const float4*)(vp + (size_t)id * 4);
  #pragma unroll
  for (int ky = 1; ky < 8; ky++){
    float4 v = *(const float4*)(vp + (size_t)ky * 131072 + (size_t)id * 4);
    s.x += v.x; s.y += v.y; s.z += v.z; s.w += v.w;
  }
  ushort2 p0 = {f2bf(s.x), f2bf(s.y)};
  ushort2 p1 = {f2bf(s.z), f2bf(s.w)};
  *(ushort2*)(hb + (size_t)id * 4)     = p0;
  *(ushort2*)(hb + (size_t)id * 4 + 2) = p1;
}

// ---------------- logits GEMM: bf16 A, single pass K=1024, 128-col tiles ----------------
__launch_bounds__(256)
__global__ void gemm_bfA_kernel(const unsigned short* __restrict__ A,
                                const float* __restrict__ W,
                                const float* __restrict__ bias,
                                float* __restrict__ C, int N)
{
  int tid = threadIdx.x;
  int wv = tid >> 6, lane = tid & 63, lr = lane & 15, lhi = lane >> 4;
  int colBase = blockIdx.x * 128 + wv * 32;
  int colL[2];
  colL[0] = min(colBase + lr, N - 1);
  colL[1] = min(colBase + 16 + lr, N - 1);

  f32x4 zero = {0.f, 0.f, 0.f, 0.f};
  f32x4 acc[8][2];
  #pragma unroll
  for (int r = 0; r < 8; r++){ acc[r][0] = zero; acc[r][1] = zero; }

  for (int ks = 0; ks < 32; ++ks){
    int k = ks * 32 + lhi * 8;
    short8 bf[2];
    #pragma unroll
    for (int cf = 0; cf < 2; cf++){
      #pragma unroll
      for (int j = 0; j < 8; j++)
        bf[cf][j] = f2bf_t(W[(size_t)(k + j) * N + colL[cf]]);
    }
    #pragma unroll
    for (int rf = 0; rf < 8; rf++){
      short8 af = *(const short8*)(A + (size_t)(rf * 16 + lr) * 1024 + k);
      acc[rf][0] = __builtin_amdgcn_mfma_f32_16x16x32_bf16(af, bf[0], acc[rf][0], 0, 0, 0);
      acc[rf][1] = __builtin_amdgcn_mfma_f32_16x16x32_bf16(af, bf[1], acc[rf][1], 0, 0, 0);
    }
  }

  #pragma unroll
  for (int cf = 0; cf < 2; cf++){
    int col = colBase + cf * 16 + lr;
    bool ok = col < N;
    float bv = bias[colL[cf]];
    #pragma unroll
    for (int rf = 0; rf < 8; rf++)
      #pragma unroll
      for (int i = 0; i < 4; i++){
        int row = rf * 16 + lhi * 4 + i;
        if (ok) C[(size_t)row * V_ + col] = acc[rf][cf][i] + bv;
      }
  }
}

// ---------------- vocab softmax (online, no store-back) + p_gen scale + fused scatter ----------------
__global__ void vocab_softmax_kernel(const float* __restrict__ lg0, const float* __restrict__ pg,
                                     const float* __restrict__ attn, const int* __restrict__ soov,
                                     float* __restrict__ fin){
  int b = blockIdx.x, t = threadIdx.x, wv = t >> 6, lane = t & 63;
  __shared__ float redm[16], reds[16];
  const float* l0 = lg0 + (size_t)b * V_;
  float m = -1e30f, s = 0.f;
  for (int i = t; i < V_; i += 1024){
    float l = l0[i];
    float mn = fmaxf(m, l);
    s = s * __expf(m - mn) + __expf(l - mn);
    m = mn;
  }
  #pragma unroll
  for (int o = 32; o > 0; o >>= 1){
    float mo = __shfl_xor(m, o), so = __shfl_xor(s, o);
    float mn = fmaxf(m, mo);
    s = s * __expf(m - mn) + so * __expf(mo - mn);
    m = mn;
  }
  if (lane == 0){ redm[wv] = m; reds[wv] = s; }
  __syncthreads();
  float M = -1e30f;
  #pragma unroll
  for (int w = 0; w < 16; w++) M = fmaxf(M, redm[w]);
  float S = 0.f;
  #pragma unroll
  for (int w = 0; w < 16; w++) S += reds[w] * __expf(redm[w] - M);
  float pgb = pg[b];
  float scale = pgb / S;
  float* fb = fin + (size_t)b * VE_;
  for (int i = t; i < V_; i += 1024) fb[i] = __expf(l0[i] - M) * scale;
  for (int i = V_ + t; i < VE_; i += 1024) fb[i] = 0.f;
  __syncthreads();
  float om = 1.f - pgb;
  if (t < 400) atomicAdd(&fb[soov[b * 400 + t]], om * attn[b * 400 + t]);
}

extern "C" void kernel_launch(void* const* d_in, const int* in_sizes, int n_in,
                              void* d_out, int out_size, void* d_ws, size_t ws_size,
                              hipStream_t stream)
{
  const int*   y     = (const int*)  d_in[0];
  const float* hin   = (const float*)d_in[1];
  const float* mb    = (const float*)d_in[2];
  const float* mask  = (const float*)d_in[3];
  const int*   soov  = (const int*)  d_in[5];
  const float* emb   = (const float*)d_in[6];
  const float* W_ih  = (const float*)d_in[7];
  const float* W_hh  = (const float*)d_in[8];
  const float* b_ih  = (const float*)d_in[9];
  const float* b_hh  = (const float*)d_in[10];
  const float* W_mem = (const float*)d_in[11];
  const float* W_dec = (const float*)d_in[12];
  const float* b_dec = (const float*)d_in[13];
  const float* vvec  = (const float*)d_in[14];
  const float* W_pg  = (const float*)d_in[15];
  const float* b_pg  = (const float*)d_in[16];
  const float* W_v1  = (const float*)d_in[17];
  const float* b_v1  = (const float*)d_in[18];
  const float* W_v2  = (const float*)d_in[19];
  const float* b_v2  = (const float*)d_in[20];

  float* out   = (float*)d_out;
  float* fin   = out;                               // [128, 50050]
  float* hnext = out + (size_t)B_ * VE_;            // [1,128,1024]
  float* ctx   = hnext + (size_t)B_ * H2_;          // [128,1024]
  float* attn  = ctx + (size_t)B_ * M_;             // [128,400]
  float* pg    = attn + (size_t)B_ * L_;            // [128]

  // workspace layout (floats); gi..scr contiguous for one-shot zeroing
  float* ws   = (float*)d_ws;
  float* yemb = ws;                                 //    65536
  float* gi   = ws + 65536;                         //   393216
  float* gh   = gi + 393216;                        //   393216
  float* dec  = gh + 393216;                        //   131072
  float* scr  = dec + 131072;                       //    51200  (gi..scr = 968,704 f)
  float* lg0  = scr + 51200;                        //  6400000
  float* vp   = lg0;                                // v1 partials alias lg0 (consumed pre-logits)
  unsigned short* hidbf = (unsigned short*)(lg0 + 6400000);   // 262144 B
  unsigned char*  WTt   = (unsigned char*)(hidbf + 131072);   // 2 MB
  unsigned char*  mbT   = WTt + 2097152;                      // 100 MB

  // pre: cvt[0,6400) | wmem | embed | zero(gi..scr) | zero(ctx)
  pre_kernel<<<8562, 256, 0, stream>>>(mb, mbT, W_mem, WTt, y, emb, yemb, gi, ctx);
  // gi+gh GEMMs + cvt[6400,12800)
  gigh_kernel<<<6544, 256, 0, stream>>>(yemb, hin, W_ih, W_hh, gi, gh, mb, mbT);
  // GRU gates + cvt[12800,19200)
  gru_gates_kernel<<<6912, 256, 0, stream>>>(gi, gh, b_ih, b_hh, hin, hnext, mb, mbT);
  // dec GEMM + cvt[19200,25600)
  dec_kernel<<<6432, 256, 0, stream>>>(hnext, W_dec, b_dec, dec, mb, mbT);

  scores_kernel<<<3200, 256, 0, stream>>>(mbT, WTt, dec, vvec, scr);
  context_kernel<<<dim3(4, 128), 256, 0, stream>>>(scr, mask, mbT, ctx, attn);

  v1_pgen_kernel<<<192, 256, 0, stream>>>(ctx, hnext, yemb, W_v1, b_v1, vp, W_pg, b_pg, pg);
  hid2bf_kernel<<<128, 256, 0, stream>>>(vp, hidbf);
  gemm_bfA_kernel<<<391, 256, 0, stream>>>(hidbf, W_v2, b_v2, lg0, V_);

  vocab_softmax_kernel<<<128, 1024, 0, stream>>>(lg0, pg, attn, soov, fin);
}